// Round 1
// baseline (84.867 us; speedup 1.0000x reference)
//
#include <hip/hip_runtime.h>

// Quantizer_189: 1-D VQ codebook lookup. x: [16,1,512,512] fp32 (N=4,194,304
// scalars; C=D=1 so transposes are no-ops), weight: [128,1].
//
// Reference model (NumPy fp32, per-op rounding, NO fma — verified, absmax 0.0):
//   dist_k = fl( fl( fl(x*x) + fl(w_k*w_k) ) - fl( fl(2x) * w_k ) )
//   idx    = np.argmin(dist) — first ORIGINAL index wins ties
//   out    = w[idx]
//
// Algorithm: sort codebook per block, binary-search insertion point, evaluate
// the EXACT reference fp32 distance on the 8 sorted candidates [pos-4, pos+3].
// (Rounding noise <= ~7e-7*x^2 ⇒ a non-window entry can win only if >=4
// codebook entries pack within ~4e-3 — negligible for 128 N(0,1) draws.)
//
// Round-5 changes (LDS-bank-conflict relief — kernel was LDS-pipe bound):
//  1. wp float2 (8B entries, 16 bank-pairs, ~8-way gather conflicts) removed.
//     Candidates read plain fp32 sv[] (32 banks, rank-uniform addresses ≈
//     2-way = free); w^2 = fl(w*w) is recomputed with a contract-off mul —
//     bit-identical to the precomputed value.
//  2. Search levels 8/4/2/1 probed strided residues of sv (structural 4-way
//     conflicts). Now per-level contiguous tables t8/t4/t2/t1 (Eytzinger
//     style): each level's addresses are contiguous → broadcast, conflict-free.
//  3. Tie-break (exact fp32-dist equality → smallest ORIGINAL index, matching
//     np.argmin) moved out of the hot loop: branchless strict-< argmin + a
//     lane tie flag accumulated on the scalar pipe; a rare post-loop fixup
//     branch re-scans the 8 candidates with si[] only when equality occurred.
//
// CRITICAL (round 1/2 lesson): device default -ffp-contract fuses mul into
// add/sub -> fma, breaking bit-exactness. Keep pragma + opaque asm barriers
// on every product (x*x, w*w, 2x*w).

constexpr int K     = 128;
constexpr int EPT   = 8;
constexpr int BLOCK = 256;

__global__ __launch_bounds__(BLOCK) void vq_kernel(const float* __restrict__ x,
                                                   const float* __restrict__ w,
                                                   float* __restrict__ out,
                                                   long n, int kk) {
#pragma clang fp contract(off)
    __shared__ float wraw[K];  // original-order codebook
    __shared__ float sv[K];    // sorted values (ascending, stable by orig idx)
    __shared__ int   si[K];    // original index per sorted pos
    __shared__ float t8[8];    // level tables: t8[k]=sv[16k+7], t4[k]=sv[8k+3],
    __shared__ float t4[16];   // t2[k]=sv[4k+1], t1[k]=sv[2k]. Contiguous per
    __shared__ float t2[32];   // level → gathers are same-address broadcasts /
    __shared__ float t1[64];   // <=2 addrs per bank → conflict-free.

    const int t = threadIdx.x;
    if (t < K) {
        wraw[t] = (t < kk) ? w[t] : __builtin_inff();
        sv[t]   = __builtin_inff();                 // pad slots
        si[t]   = 0x7fffffff;
    }
    __syncthreads();
    if (t < kk) {
        // Stable O(K) rank sort: rank = #{strictly less} + #{equal, earlier}.
        float v = wraw[t];
        int rank = 0;
        for (int j = 0; j < kk; ++j) {
            float u = wraw[j];
            rank += (u < v) || (u == v && j < t);
        }
        sv[rank] = v;
        si[rank] = t;
    }
    __syncthreads();
    if (t < 64) t1[t] = sv[2 * t];
    if (t < 32) t2[t] = sv[4 * t + 1];
    if (t < 16) t4[t] = sv[8 * t + 3];
    if (t < 8)  t8[t] = sv[16 * t + 7];
    __syncthreads();

    // First 3 search levels from registers (block-uniform values).
    const float m1  = sv[63];
    const float m2a = sv[31],  m2b = sv[95];
    const float m3a = sv[15],  m3b = sv[47], m3c = sv[79], m3d = sv[111];
    const int smax = (kk > 8 ? kk : 8) - 8;

    long base = ((long)blockIdx.x * BLOCK + t) * (long)EPT;
    if (base + EPT <= n) {
        float4 a = *(const float4*)(x + base);
        float4 b = *(const float4*)(x + base + 4);
        float xs[EPT] = {a.x, a.y, a.z, a.w, b.x, b.y, b.z, b.w};
        float res[EPT];
#pragma unroll
        for (int e = 0; e < EPT; ++e) {
            float xv = xs[e];
            float x2 = xv * xv;            // fl(x*x)
            asm volatile("" : "+v"(x2));   // block fma(x,x,w2)
            float tx = xv + xv;            // fl(2x), exact

            // Branchless lower_bound: pos = #{sv < xv}. Levels 64/32/16 from
            // registers, 8/4/2/1 from conflict-free level tables.
            int pos = (m1 < xv) ? 64 : 0;
            float m2 = (pos & 64) ? m2b : m2a;
            pos += (m2 < xv) ? 32 : 0;
            float m3lo = (pos & 32) ? m3b : m3a;
            float m3hi = (pos & 32) ? m3d : m3c;
            float m3   = (pos & 64) ? m3hi : m3lo;
            pos += (m3 < xv) ? 16 : 0;
            pos += (t8[pos >> 4] < xv) ? 8 : 0;   // = sv[pos+7]
            pos += (t4[pos >> 3] < xv) ? 4 : 0;   // = sv[pos+3]
            pos += (t2[pos >> 2] < xv) ? 2 : 0;   // = sv[pos+1]
            pos += (t1[pos >> 1] < xv) ? 1 : 0;   // = sv[pos]

            // Candidate window [pos-4, pos+3], clamped.
            int s = pos - 4;
            s = s < 0 ? 0 : (s > smax ? smax : s);

            float best = __builtin_inff();
            float bw   = 0.0f;
            unsigned tie = 0u;               // lane flag: exact d-equality seen
#pragma unroll
            for (int c = 0; c < 8; ++c) {
                float wv = sv[s + c];
                float w2 = wv * wv;             // fl(w*w), == precomputed value
                asm volatile("" : "+v"(w2));    // keep standalone product
                float sum  = x2 + w2;           // fl(x^2 + w^2)
                float prod = tx * wv;           // fl(2x * w)
                asm volatile("" : "+v"(prod));  // block fma fusion into sub
                float d = sum - prod;           // fl(sum - prod)
                bool lt = d < best;
                tie |= (d == best) ? 1u : 0u;   // equality vs running best
                best = lt ? d : best;
                bw   = lt ? wv : bw;
            }
            res[e] = bw;
            // Rare exact-tie fixup (equality against the running best implies
            // any final-best tie is flagged). np.argmin: smallest ORIGINAL idx.
            if (__builtin_expect(tie != 0u, 0)) {
                float bb = __builtin_inff(), bwv = 0.0f;
                int bi = 0x7fffffff;
                for (int c = 0; c < 8; ++c) {
                    float wv = sv[s + c];
                    float w2 = wv * wv;
                    asm volatile("" : "+v"(w2));
                    float sum  = x2 + w2;
                    float prod = tx * wv;
                    asm volatile("" : "+v"(prod));
                    float d = sum - prod;
                    int oi = si[s + c];
                    if (d < bb || (d == bb && oi < bi)) { bb = d; bi = oi; bwv = wv; }
                }
                res[e] = bwv;
            }
        }
        *(float4*)(out + base)     = make_float4(res[0], res[1], res[2], res[3]);
        *(float4*)(out + base + 4) = make_float4(res[4], res[5], res[6], res[7]);
    } else {
        // Tail (not hit for N=4,194,304): exact brute force over kk entries.
        for (long i = base; i < n; ++i) {
            float xv = x[i];
            float x2 = xv * xv;
            asm volatile("" : "+v"(x2));
            float tx = xv + xv;
            float bb = __builtin_inff(), bwv = 0.0f;
            int bi = 0x7fffffff;
            for (int p0 = 0; p0 < kk; ++p0) {
                float wv = sv[p0];
                float w2 = wv * wv;
                asm volatile("" : "+v"(w2));
                float sum  = x2 + w2;
                float prod = tx * wv;
                asm volatile("" : "+v"(prod));
                float d = sum - prod;
                int oi = si[p0];
                if (d < bb || (d == bb && oi < bi)) { bb = d; bi = oi; bwv = wv; }
            }
            out[i] = bwv;
        }
    }
}

extern "C" void kernel_launch(void* const* d_in, const int* in_sizes, int n_in,
                              void* d_out, int out_size, void* d_ws, size_t ws_size,
                              hipStream_t stream) {
    const float* x = (const float*)d_in[0];
    const float* w = (const float*)d_in[1];
    float* out     = (float*)d_out;
    long n = (long)in_sizes[0];
    int  kk = in_sizes[1] < K ? in_sizes[1] : K;

    long threads_needed = (n + EPT - 1) / EPT;
    long grid = (threads_needed + BLOCK - 1) / BLOCK;
    vq_kernel<<<(int)grid, BLOCK, 0, stream>>>(x, w, out, n, kk);
}